// Round 5
// baseline (6826.643 us; speedup 1.0000x reference)
//
#include <hip/hip_runtime.h>

typedef unsigned short ushort_t;
typedef __bf16 bf16x8 __attribute__((ext_vector_type(8)));
typedef float f32x4 __attribute__((ext_vector_type(4)));
typedef unsigned int u32x4 __attribute__((ext_vector_type(4)));
typedef unsigned int u32x2 __attribute__((ext_vector_type(2)));

#define T_STEPS 512
#define BATCH 64
#define HDIM 1024
#define CHUNK 32                 // steps per gate-precompute chunk
#define NCHUNK (T_STEPS / CHUNK) // 16
#define MCH (CHUNK * BATCH)      // 2048 rows per chunk GEMM
#define OUTS_ELEMS 33554432ULL
#define NWG 128                  // persistent WGs; 1/CU (LDS-bound) => co-resident

// LDS: h buffer 128 KiB (swizzled) + Hw gather 1 KiB
#define HS_BYTES   131072
#define SMEM_BYTES (HS_BYTES + 1024)

// ---- coherent (LLC-level, cross-XCD) access: sc0 sc1 bypass L1+L2 ----
#define GLOAD16_COH(dst, src) \
    asm volatile("global_load_dwordx4 %0, %1, off sc0 sc1" : "=v"(dst) : "v"(src) : "memory")
#define GLOAD8_CACHED(dst, src) \
    asm volatile("global_load_dwordx2 %0, %1, off" : "=v"(dst) : "v"(src) : "memory")
#define GSTORE16_COH(dst, val) \
    asm volatile("global_store_dwordx4 %0, %1, off sc0 sc1" :: "v"(dst), "v"(val) : "memory")
// counted vmcnt wait, register-tied so consumers can't be hoisted above it
#define WAITVM8(N, R) \
    asm volatile("s_waitcnt vmcnt(" #N ")" \
        : "+v"(R[0]), "+v"(R[1]), "+v"(R[2]), "+v"(R[3]), \
          "+v"(R[4]), "+v"(R[5]), "+v"(R[6]), "+v"(R[7]) :: "memory")
#define WAITVM0_TIE(R, G) \
    asm volatile("s_waitcnt vmcnt(0)" \
        : "+v"(R[0]), "+v"(R[1]), "+v"(R[2]), "+v"(R[3]), \
          "+v"(R[4]), "+v"(R[5]), "+v"(R[6]), "+v"(R[7]), \
          "+v"(G[0]), "+v"(G[1]), "+v"(G[2]), "+v"(G[3]), \
          "+v"(G[4]), "+v"(G[5]), "+v"(G[6]), "+v"(G[7]) :: "memory")
// raw workgroup barrier: LDS-visibility only, does NOT drain vmcnt
#define WGBAR() do { asm volatile("s_waitcnt lgkmcnt(0)" ::: "memory"); \
                     __builtin_amdgcn_s_barrier(); } while (0)

__device__ __forceinline__ ushort_t f2bf(float f) {
    union { unsigned int i; float f; } v;
    v.f = f;
    unsigned int x = v.i;
    unsigned int r = (x + 0x7FFFu + ((x >> 16) & 1u)) >> 16;
    return (ushort_t)r;
}

__device__ __forceinline__ float bf2f(ushort_t u) {
    union { unsigned int i; float f; } v;
    v.i = ((unsigned int)u) << 16;
    return v.f;
}

struct Ptr8 { const float* p[8]; };
struct Ptr4 { const float* p[4]; };

// ---------------------------------------------------------------------------
// Transpose+convert 8 fp32 weights [1024 k][1024 n] -> bf16 [4096 n''][1024 k]
// with INTERLEAVED rows: n'' = n*4 + gate  (gate = z&3; z<4 -> wt_x, z>=4 -> wt_h)
// ---------------------------------------------------------------------------
__global__ __launch_bounds__(256) void transpose8(Ptr8 in, ushort_t* __restrict__ out) {
    __shared__ ushort_t tile[64][65];
    int z = blockIdx.z;
    const float* src = in.p[z];
    ushort_t* dst = out + (size_t)(z >> 2) * 4194304;  // wt_x block then wt_h block
    int gate = z & 3;
    int bx = blockIdx.x * 64;  // n base
    int by = blockIdx.y * 64;  // k base
    int t = threadIdx.x;
#pragma unroll
    for (int i = 0; i < 16; i++) {
        int lin = t + i * 256;
        int r = lin >> 6, c = lin & 63;
        tile[r][c] = f2bf(src[(size_t)(by + r) * 1024 + bx + c]);
    }
    __syncthreads();
#pragma unroll
    for (int i = 0; i < 16; i++) {
        int lin = t + i * 256;
        int r = lin >> 6, c = lin & 63;
        dst[((size_t)(bx + r) * 4 + gate) * 1024 + by + c] = tile[c][r];
    }
}

// ---------------------------------------------------------------------------
// Chunk GEMM: G[m][n''] = A[m][:] @ wt_x[n''][:] + bias[n'']   (interleaved n'')
// ---------------------------------------------------------------------------
#define BK 32
#define LDK 40

__global__ __launch_bounds__(256) void chunk_gemm(
    const float* __restrict__ A,
    const ushort_t* __restrict__ Wt,
    Ptr4 biases,
    ushort_t* __restrict__ G)            // [2048 m][4096 n'']
{
    __shared__ ushort_t As[128 * LDK];
    __shared__ ushort_t Bs[128 * LDK];

    int n0 = blockIdx.x * 128;
    int m0 = blockIdx.y * 128;
    int t = threadIdx.x;
    int wave = t >> 6, lane = t & 63;
    int wm = (wave & 1) * 64, wn = (wave >> 1) * 64;
    int lrow = lane & 15, quad = lane >> 4;
    int lk = quad * 8;

    f32x4 acc[4][4] = {};

    for (int k0 = 0; k0 < 1024; k0 += BK) {
        __syncthreads();
#pragma unroll
        for (int i = 0; i < 4; i++) {
            int c = t + 256 * i;
            int r = c >> 3, kc = c & 7;
            const float4 v = *(const float4*)&A[(size_t)(m0 + r) * 1024 + k0 + kc * 4];
            ushort_t* d = &As[r * LDK + kc * 4];
            d[0] = f2bf(v.x); d[1] = f2bf(v.y); d[2] = f2bf(v.z); d[3] = f2bf(v.w);
        }
#pragma unroll
        for (int i = 0; i < 2; i++) {
            int c = t + 256 * i;
            int r = c >> 2, kc = c & 3;
            *(bf16x8*)&Bs[r * LDK + kc * 8] =
                *(const bf16x8*)&Wt[(size_t)(n0 + r) * 1024 + k0 + kc * 8];
        }
        __syncthreads();

        bf16x8 a[4], b[4];
#pragma unroll
        for (int i = 0; i < 4; i++)
            a[i] = *(const bf16x8*)&As[(wm + i * 16 + lrow) * LDK + lk];
#pragma unroll
        for (int j = 0; j < 4; j++)
            b[j] = *(const bf16x8*)&Bs[(wn + j * 16 + lrow) * LDK + lk];
#pragma unroll
        for (int i = 0; i < 4; i++)
#pragma unroll
            for (int j = 0; j < 4; j++)
                acc[i][j] = __builtin_amdgcn_mfma_f32_16x16x32_bf16(a[i], b[j], acc[i][j], 0, 0, 0);
    }

    const float* b0 = biases.p[0];
    const float* b1 = biases.p[1];
    const float* b2 = biases.p[2];
    const float* b3 = biases.p[3];
#pragma unroll
    for (int j = 0; j < 4; j++) {
        int coln = n0 + wn + j * 16 + lrow;
        // n'' = unit*4 + gate
        const float* bp = (coln & 1) ? ((coln & 2) ? b3 : b1)
                                     : ((coln & 2) ? b2 : b0);
        float bv = bp[coln >> 2];
#pragma unroll
        for (int i = 0; i < 4; i++) {
#pragma unroll
            for (int r = 0; r < 4; r++) {
                int rowm = m0 + wm + i * 16 + quad * 4 + r;
                G[(size_t)rowm * 4096 + coln] = f2bf(acc[i][j][r] + bv);
            }
        }
    }
}

// ---------------------------------------------------------------------------
// Init state + zero barrier flags
// ---------------------------------------------------------------------------
__global__ __launch_bounds__(256) void init_state(
    const float* __restrict__ h0, const float* __restrict__ c0,
    float* __restrict__ hf, float* __restrict__ cf, ushort_t* __restrict__ hb,
    unsigned* __restrict__ flags)
{
    int i = blockIdx.x * 256 + threadIdx.x;  // 65536
    float h = h0[i];
    hf[i] = h;
    cf[i] = c0[i];
    hb[i] = f2bf(h);
    if (blockIdx.x == 0 && threadIdx.x < NWG) flags[threadIdx.x] = 0;
}

// ---------------------------------------------------------------------------
// Persistent per-chunk recurrence. Per step:
//   - 32 coherent coalesced h loads -> single 128-KiB swizzled LDS buffer
//     (2-deep batched counted-vmcnt pipeline, ONE barrier)
//   - 32 K-slices: ds_read A (2) + L2-cached B + 2 MFMA (acc = full K sum)
//   - gate layout interleaved (vc = unit*4+g) => epilogue gate exchange is
//     32 __shfl within the wave: NO S-LDS, NO extra barriers
//   - Hw gather (1 KiB) -> barrier -> wave0 coherent 16-B h stores -> flag
// ---------------------------------------------------------------------------
__device__ __forceinline__ void issue8(const ushort_t* __restrict__ hb, int tid, int j,
                                       u32x4 (&R)[8]) {
#pragma unroll
    for (int k = 0; k < 8; k++) {
        const ushort_t* src = hb + (size_t)(tid + (j * 8 + k) * 256) * 8;
        GLOAD16_COH(R[k], src);
    }
}

__device__ __forceinline__ void write8(char* Hs, int tid, int j, u32x4 (&R)[8]) {
#pragma unroll
    for (int k = 0; k < 8; k++) {
        int s = tid + (j * 8 + k) * 256;              // 16-B slot; b = s>>7
        *(u32x4*)(Hs + ((s * 16) ^ (((s >> 7) & 7) << 4))) = R[k];
    }
}

__global__ __launch_bounds__(256, 1) void lstm_chunk(
    const ushort_t* __restrict__ WtH,   // bf16 [4096 n''][1024 k], n''=unit*4+g
    const ushort_t* __restrict__ Gc,    // bf16 [2048 m][4096 n'']
    const float* __restrict__ ret,      // fp32 [1024]
    float* __restrict__ cf_g,           // fp32 chunk-boundary state
    float* __restrict__ hf_g,           // fp32 chunk-boundary state
    ushort_t* __restrict__ hb0,         // bf16 h ping
    ushort_t* __restrict__ hb1,         // bf16 h pong
    float* __restrict__ out,            // d_out fp32
    unsigned* __restrict__ flags,       // [NWG] barrier flags (monotonic)
    int c)                              // chunk index
{
    extern __shared__ char smem[];
    char* Hs = smem;                                  // 128 KiB swizzled h
    ushort_t* Hw = (ushort_t*)(smem + HS_BYTES);      // 1 KiB gather

    const int tid = threadIdx.x;
    const int wg = blockIdx.x;
    const int u0 = wg * 8;
    const int wave = tid >> 6, lane = tid & 63;
    const int lrow = lane & 15, quad = lane >> 4;
    const int g_self = lane & 3;
    const int mh = (wave & 1) * 32;                   // batch half
    const int wn = (wave >> 1) * 16;                  // vc-tile base (0/16)
    const int uu = (wave >> 1) * 4 + ((lane >> 2) & 3);
    const int ucol = u0 + uu;                         // global unit
    const int arow0 = mh + lrow;
    const int swz = (arow0 & 7) << 4;                 // same for arow0+16

    // ---- persistent state in registers; 8 (b,u) per lane (x4 dup over g) ----
    float hf_r[2][4], cf_r[2][4];
    float rr = ret[ucol];
#pragma unroll
    for (int mt = 0; mt < 2; mt++)
#pragma unroll
        for (int r = 0; r < 4; r++) {
            int idx = (mh + mt * 16 + quad * 4 + r) * 1024 + ucol;
            hf_r[mt][r] = hf_g[idx];
            cf_r[mt][r] = cf_g[idx];
        }
    __syncthreads();
    asm volatile("s_waitcnt vmcnt(0) lgkmcnt(0)" ::: "memory");

    const ushort_t* wrow = WtH + (size_t)(wg * 32 + wn + lrow) * 1024 + quad * 8;
    const unsigned tbase = (unsigned)c * (unsigned)(CHUNK - 1);

#pragma unroll 1
    for (int tc = 0; tc < CHUNK; tc++) {
        const int t = c * CHUNK + tc;
        const ushort_t* hb_in = (tc & 1) ? hb1 : hb0;
        ushort_t* hb_out      = (tc & 1) ? hb0 : hb1;

        // ---- gate-precompute: 8 x dwordx2 cached loads (issued FIRST) ----
        u32x2 gp[8];
#pragma unroll
        for (int mt = 0; mt < 2; mt++)
#pragma unroll
            for (int r = 0; r < 4; r++) {
                const ushort_t* src = Gc + (size_t)(tc * 64 + mh + mt * 16 + quad * 4 + r) * 4096
                                         + (size_t)ucol * 4;
                GLOAD8_CACHED(gp[mt * 4 + r], src);
            }

        // ---- stage h: 4 batches of 8, 2-deep pipeline, counted vmcnt ----
        u32x4 RA[8], RB[8], RC[8], RD[8];
        issue8(hb_in, tid, 0, RA);
        issue8(hb_in, tid, 1, RB);
        WAITVM8(8, RA);  write8(Hs, tid, 0, RA);      // gp+A retired
        issue8(hb_in, tid, 2, RC);
        WAITVM8(8, RB);  write8(Hs, tid, 1, RB);
        issue8(hb_in, tid, 3, RD);
        WAITVM8(8, RC);  write8(Hs, tid, 2, RC);
        WAITVM0_TIE(RD, gp);  write8(Hs, tid, 3, RD);
        WGBAR();                                       // h staged (1 barrier)

        // ---- GEMM: 32 K-slices, full-K accumulate, B from L2 ----
        f32x4 acc[2] = {};
#pragma unroll
        for (int s = 0; s < 32; s++) {
            bf16x8 b  = *(const bf16x8*)(wrow + s * 32);
            bf16x8 a0 = *(const bf16x8*)(Hs + ((arow0 * 2048 + s * 64 + quad * 16) ^ swz));
            bf16x8 a1 = *(const bf16x8*)(Hs + (((arow0 + 16) * 2048 + s * 64 + quad * 16) ^ swz));
            acc[0] = __builtin_amdgcn_mfma_f32_16x16x32_bf16(a0, b, acc[0], 0, 0, 0);
            acc[1] = __builtin_amdgcn_mfma_f32_16x16x32_bf16(a1, b, acc[1], 0, 0, 0);
        }

        // ---- epilogue: gate exchange via __shfl (adjacent-lane gates) ----
        float hn_s[2][4];
        const int srcb = lane & 60;
#pragma unroll
        for (int mt = 0; mt < 2; mt++) {
            float gv0[4], gv1[4], gv2[4], gv3[4];
#pragma unroll
            for (int r = 0; r < 4; r++) {
                gv0[r] = __shfl(acc[mt][r], srcb, 64);
                gv1[r] = __shfl(acc[mt][r], srcb | 1, 64);
                gv2[r] = __shfl(acc[mt][r], srcb | 2, 64);
                gv3[r] = __shfl(acc[mt][r], srcb | 3, 64);
            }
#pragma unroll
            for (int r = 0; r < 4; r++) {
                u32x2 g2 = gp[mt * 4 + r];
                float si = gv0[r] + bf2f((ushort_t)(g2.x & 0xffff));
                float sf = gv1[r] + bf2f((ushort_t)(g2.x >> 16));
                float so = gv2[r] + bf2f((ushort_t)(g2.y & 0xffff));
                float sc = gv3[r] + bf2f((ushort_t)(g2.y >> 16));
                float it = 1.f / (1.f + __expf(-si));
                float ft = 1.f / (1.f + __expf(-sf));
                float ot = 1.f / (1.f + __expf(-so));
                float gt = 1.f - 2.f / (__expf(2.f * sc) + 1.f);   // NaN-safe tanh
                float cn = cf_r[mt][r] * ft + it * gt;
                float tcn = 1.f - 2.f / (__expf(2.f * cn) + 1.f);  // NaN-safe tanh
                float hl = ot * tcn;
                float hn = rr * hf_r[mt][r] + (1.f - rr) * hl;
                cf_r[mt][r] = cn;
                hf_r[mt][r] = hn;
                hn_s[mt][r] = hn;
                if (g_self == 0) {
                    int b = mh + mt * 16 + quad * 4 + r;
                    Hw[b * 8 + uu] = f2bf(hn);
                }
            }
        }
        WGBAR();   // Hw complete

        // ---- wave0: gathered coherent h stores (64 x 16 B) + ack ----
        if (tid < 64) {
            u32x4 v = *(const u32x4*)&Hw[tid * 8];
            ushort_t* dst = hb_out + (size_t)tid * 1024 + u0;
            GSTORE16_COH(dst, v);
            asm volatile("s_waitcnt vmcnt(0)" ::: "memory");
        }
        if (tc < CHUNK - 1 && tid == 0)
            __hip_atomic_store(&flags[wg], tbase + (unsigned)tc + 1u,
                               __ATOMIC_RELAXED, __HIP_MEMORY_SCOPE_AGENT);

        // ---- out NT stores (off the release critical path; writers only) ----
        if (g_self == 0) {
#pragma unroll
            for (int mt = 0; mt < 2; mt++)
#pragma unroll
                for (int r = 0; r < 4; r++) {
                    int b = mh + mt * 16 + quad * 4 + r;
                    __builtin_nontemporal_store(hn_s[mt][r],
                        &out[(size_t)t * 65536 + b * 1024 + ucol]);
                }
        }

        // ---- grid barrier between steps ----
        if (tc < CHUNK - 1) {
            unsigned target = tbase + (unsigned)tc + 1u;
            if (tid < NWG)
                while (__hip_atomic_load(&flags[tid], __ATOMIC_RELAXED,
                                         __HIP_MEMORY_SCOPE_AGENT) < target) {}
            WGBAR();
            asm volatile("s_waitcnt vmcnt(0)" ::: "memory");  // drain polls + NT stores
        }
    }

    // ---- write back chunk-boundary state (writers only) ----
    if (g_self == 0) {
#pragma unroll
        for (int mt = 0; mt < 2; mt++)
#pragma unroll
            for (int r = 0; r < 4; r++) {
                int idx = (mh + mt * 16 + quad * 4 + r) * 1024 + ucol;
                hf_g[idx] = hf_r[mt][r];
                cf_g[idx] = cf_r[mt][r];
            }
    }
}

// ---------------------------------------------------------------------------
// Epilogue: append h_T and c_T (fp32) to d_out
// ---------------------------------------------------------------------------
__global__ __launch_bounds__(256) void epilogue_k(
    const float* __restrict__ hf_final, const float* __restrict__ cf,
    float* __restrict__ out)
{
    int i = blockIdx.x * 256 + threadIdx.x;  // 65536
    out[OUTS_ELEMS + i] = hf_final[i];
    out[OUTS_ELEMS + 65536 + i] = cf[i];
}

// ---------------------------------------------------------------------------
extern "C" void kernel_launch(void* const* d_in, const int* in_sizes, int n_in,
                              void* d_out, int out_size, void* d_ws, size_t ws_size,
                              hipStream_t stream)
{
    const float* input_ = (const float*)d_in[0];
    const float* h0   = (const float*)d_in[1];
    const float* c0   = (const float*)d_in[2];
    const float* w_xi = (const float*)d_in[3];
    const float* w_xf = (const float*)d_in[4];
    const float* w_xo = (const float*)d_in[5];
    const float* w_xc = (const float*)d_in[6];
    const float* w_hi = (const float*)d_in[7];
    const float* w_hf = (const float*)d_in[8];
    const float* w_ho = (const float*)d_in[9];
    const float* w_hc = (const float*)d_in[10];
    const float* b_i  = (const float*)d_in[11];
    const float* b_f  = (const float*)d_in[12];
    const float* b_o  = (const float*)d_in[13];
    const float* b_c  = (const float*)d_in[14];
    const float* ret  = (const float*)d_in[15];

    // workspace carve (~33.6 MiB)
    ushort_t* wt_x   = (ushort_t*)d_ws;            // 4*1M bf16  (8 MiB), n''-interleaved
    ushort_t* wt_h   = wt_x + 4ULL * 1048576;      // 4*1M bf16  (8 MiB), n''-interleaved
    ushort_t* gchunk = wt_h + 4ULL * 1048576;      // 2048*4096 bf16 (16 MiB)
    float*  cf  = (float*)(gchunk + (size_t)MCH * 4096);
    float*  hf0 = cf + 65536;
    float*  hf1 = hf0 + 65536;                     // (unused; carve kept stable)
    ushort_t* hb0 = (ushort_t*)(hf1 + 65536);
    ushort_t* hb1 = hb0 + 65536;
    unsigned* flags = (unsigned*)(hb1 + 65536);    // NWG barrier flags
    float* out = (float*)d_out;

    static bool attr_set = false;
    if (!attr_set) {
        hipFuncSetAttribute(reinterpret_cast<const void*>(lstm_chunk),
                            hipFuncAttributeMaxDynamicSharedMemorySize, SMEM_BYTES);
        attr_set = true;
    }

    Ptr8 p8; p8.p[0] = w_xi; p8.p[1] = w_xf; p8.p[2] = w_xo; p8.p[3] = w_xc;
             p8.p[4] = w_hi; p8.p[5] = w_hf; p8.p[6] = w_ho; p8.p[7] = w_hc;
    transpose8<<<dim3(16, 16, 8), 256, 0, stream>>>(p8, wt_x);

    init_state<<<256, 256, 0, stream>>>(h0, c0, hf0, cf, hb0, flags);

    Ptr4 b4; b4.p[0] = b_i; b4.p[1] = b_f; b4.p[2] = b_o; b4.p[3] = b_c;

    for (int chunk = 0; chunk < NCHUNK; chunk++) {
        chunk_gemm<<<dim3(32, 16), 256, 0, stream>>>(
            input_ + (size_t)chunk * MCH * 1024, wt_x, b4, gchunk);
        lstm_chunk<<<NWG, 256, SMEM_BYTES, stream>>>(
            wt_h, gchunk, ret, cf, hf0, hb0, hb1, out, flags, chunk);
    }

    epilogue_k<<<256, 256, 0, stream>>>(hf0, cf, out);
}

// Round 6
// 4475.406 us; speedup vs baseline: 1.5254x; 1.5254x over previous
//
#include <hip/hip_runtime.h>

typedef unsigned short ushort_t;
typedef __bf16 bf16x8 __attribute__((ext_vector_type(8)));
typedef float f32x4 __attribute__((ext_vector_type(4)));
typedef unsigned int u32x4 __attribute__((ext_vector_type(4)));

#define T_STEPS 512
#define BATCH 64
#define HDIM 1024
#define CHUNK 32                 // steps per gate-precompute chunk
#define NCHUNK (T_STEPS / CHUNK) // 16
#define MCH (CHUNK * BATCH)      // 2048 rows per chunk GEMM
#define OUTS_ELEMS 33554432ULL
#define NWG 128                  // recurrence WGs; + 128 gemm WGs = 256 = #CUs

#define S_STRIDE 36              // padded fp32 row stride for S exchange

// ---- LDS carve for lstm_fused (dynamic) ----
#define WS_BYTES   65536                       // W_h slice: 32 vc x 1024 k bf16, swizzled
#define HQ_BYTES   32768                       // h quarter: 64 b x 256 k bf16, swizzled
#define S_BYTES    (2 * 64 * S_STRIDE * 4)     // 18432
#define GG_BYTES   (64 * 32 * 2)               // 4096
#define HW_BYTES   (64 * 8 * 2)                // 1024
#define SMEM_BYTES (WS_BYTES + 2 * HQ_BYTES + S_BYTES + GG_BYTES + HW_BYTES) // 154624

// ---- coherent (LLC-level, cross-XCD) access: sc0 sc1 bypass L1+L2 ----
#define GLOAD16_COH(dst, src) \
    asm volatile("global_load_dwordx4 %0, %1, off sc0 sc1" : "=v"(dst) : "v"(src) : "memory")
#define GLOAD16_CACHED(dst, src) \
    asm volatile("global_load_dwordx4 %0, %1, off" : "=v"(dst) : "v"(src) : "memory")
#define GSTORE16_COH(dst, val) \
    asm volatile("global_store_dwordx4 %0, %1, off sc0 sc1" :: "v"(dst), "v"(val) : "memory")
// counted vmcnt wait, register-tied so consumers can't be hoisted above it
#define WAITVM8(N, R) \
    asm volatile("s_waitcnt vmcnt(" #N ")" \
        : "+v"(R[0]), "+v"(R[1]), "+v"(R[2]), "+v"(R[3]), \
          "+v"(R[4]), "+v"(R[5]), "+v"(R[6]), "+v"(R[7]) :: "memory")
// raw workgroup barrier: LDS-visibility only, does NOT drain vmcnt
#define WGBAR() do { asm volatile("s_waitcnt lgkmcnt(0)" ::: "memory"); \
                     __builtin_amdgcn_s_barrier(); } while (0)

__device__ __forceinline__ ushort_t f2bf(float f) {
    union { unsigned int i; float f; } v;
    v.f = f;
    unsigned int x = v.i;
    unsigned int r = (x + 0x7FFFu + ((x >> 16) & 1u)) >> 16;
    return (ushort_t)r;
}

__device__ __forceinline__ float bf2f(ushort_t u) {
    union { unsigned int i; float f; } v;
    v.i = ((unsigned int)u) << 16;
    return v.f;
}

struct Ptr8 { const float* p[8]; };
struct Ptr4 { const float* p[4]; };

// ---------------------------------------------------------------------------
// Transpose+convert 8 fp32 weight matrices [1024 k][1024 n] -> bf16 [1024 n][1024 k]
// ---------------------------------------------------------------------------
__global__ __launch_bounds__(256) void transpose8(Ptr8 in, ushort_t* __restrict__ out) {
    __shared__ ushort_t tile[64][65];
    int z = blockIdx.z;
    const float* src = in.p[z];
    ushort_t* dst = out + (size_t)z * 1024 * 1024;
    int bx = blockIdx.x * 64;  // n base
    int by = blockIdx.y * 64;  // k base
    int t = threadIdx.x;
#pragma unroll
    for (int i = 0; i < 16; i++) {
        int lin = t + i * 256;
        int r = lin >> 6, c = lin & 63;
        tile[r][c] = f2bf(src[(size_t)(by + r) * 1024 + bx + c]);
    }
    __syncthreads();
#pragma unroll
    for (int i = 0; i < 16; i++) {
        int lin = t + i * 256;
        int r = lin >> 6, c = lin & 63;
        dst[(size_t)(bx + r) * 1024 + by + c] = tile[c][r];
    }
}

// ---------------------------------------------------------------------------
// Shared GEMM tile body (used by standalone chunk_gemm and the fused kernel's
// gemm half). G[m][n'] = A[m][:] @ Wt[n'][:] + bias.
// ---------------------------------------------------------------------------
#define BK 32
#define LDK 40

__device__ __forceinline__ void gemm_tile(
    const float* __restrict__ A, const ushort_t* __restrict__ Wt, Ptr4 biases,
    ushort_t* __restrict__ G, ushort_t* As, ushort_t* Bs, int n0, int m0, int t)
{
    int wave = t >> 6, lane = t & 63;
    int wm = (wave & 1) * 64, wn = (wave >> 1) * 64;
    int lrow = lane & 15, quad = lane >> 4;
    int lk = quad * 8;

    f32x4 acc[4][4] = {};

    for (int k0 = 0; k0 < 1024; k0 += BK) {
        __syncthreads();
#pragma unroll
        for (int i = 0; i < 4; i++) {
            int c = t + 256 * i;
            int r = c >> 3, kc = c & 7;
            const float4 v = *(const float4*)&A[(size_t)(m0 + r) * 1024 + k0 + kc * 4];
            ushort_t* d = &As[r * LDK + kc * 4];
            d[0] = f2bf(v.x); d[1] = f2bf(v.y); d[2] = f2bf(v.z); d[3] = f2bf(v.w);
        }
#pragma unroll
        for (int i = 0; i < 2; i++) {
            int c = t + 256 * i;
            int r = c >> 2, kc = c & 3;
            *(bf16x8*)&Bs[r * LDK + kc * 8] =
                *(const bf16x8*)&Wt[(size_t)(n0 + r) * 1024 + k0 + kc * 8];
        }
        __syncthreads();

        bf16x8 a[4], b[4];
#pragma unroll
        for (int i = 0; i < 4; i++)
            a[i] = *(const bf16x8*)&As[(wm + i * 16 + lrow) * LDK + lk];
#pragma unroll
        for (int j = 0; j < 4; j++)
            b[j] = *(const bf16x8*)&Bs[(wn + j * 16 + lrow) * LDK + lk];
#pragma unroll
        for (int i = 0; i < 4; i++)
#pragma unroll
            for (int j = 0; j < 4; j++)
                acc[i][j] = __builtin_amdgcn_mfma_f32_16x16x32_bf16(a[i], b[j], acc[i][j], 0, 0, 0);
    }

    int g = n0 >> 10;
    const float* bias = biases.p[g];
    int cg0 = (n0 & 1023) + wn;
#pragma unroll
    for (int j = 0; j < 4; j++) {
        int coln = n0 + wn + j * 16 + lrow;
        float bv = bias[cg0 + j * 16 + lrow];
#pragma unroll
        for (int i = 0; i < 4; i++) {
#pragma unroll
            for (int r = 0; r < 4; r++) {
                int rowm = m0 + wm + i * 16 + quad * 4 + r;
                G[(size_t)rowm * 4096 + coln] = f2bf(acc[i][j][r] + bv);
            }
        }
    }
}

__global__ __launch_bounds__(256) void chunk_gemm(
    const float* __restrict__ A,
    const ushort_t* __restrict__ Wt,
    Ptr4 biases,
    ushort_t* __restrict__ G)
{
    __shared__ ushort_t As[128 * LDK];
    __shared__ ushort_t Bs[128 * LDK];
    gemm_tile(A, Wt, biases, G, As, Bs, blockIdx.x * 128, blockIdx.y * 128, threadIdx.x);
}

// ---------------------------------------------------------------------------
// Init state + zero barrier flags (fresh per launch / graph replay)
// ---------------------------------------------------------------------------
__global__ __launch_bounds__(256) void init_state(
    const float* __restrict__ h0, const float* __restrict__ c0,
    float* __restrict__ hf, float* __restrict__ cf, ushort_t* __restrict__ hb,
    unsigned* __restrict__ flags)
{
    int i = blockIdx.x * 256 + threadIdx.x;  // 65536
    float h = h0[i];
    hf[i] = h;
    cf[i] = c0[i];
    hb[i] = f2bf(h);
    if (blockIdx.x == 0 && threadIdx.x < NWG) flags[threadIdx.x] = 0;
}

// ---------------------------------------------------------------------------
// Fused persistent kernel, 256 WGs (1/CU):
//   WGs 0..127   : R2-verified per-chunk recurrence on Gc_cur (32 steps)
//   WGs 128..255 : next chunk's gate GEMM into Gc_next (4 tiles each)
// The two halves are independent; the dispatch boundary is the producer->
// consumer sync for Gc. LDS 151 KiB forces 1 WG/CU so all 256 co-reside.
// ---------------------------------------------------------------------------
__device__ __forceinline__ void qload(const ushort_t* __restrict__ hb_in, int q,
                                      int tid, u32x4 (&R)[8]) {
#pragma unroll
    for (int j = 0; j < 8; j++) {
        int s = tid + j * 256;
        const ushort_t* src = hb_in + (size_t)(s >> 5) * 1024 + q * 256 + ((s & 31) << 3);
        GLOAD16_COH(R[j], src);
    }
}

__device__ __forceinline__ void qwrite(char* buf, int tid, u32x4 (&R)[8]) {
#pragma unroll
    for (int j = 0; j < 8; j++) {
        int s = tid + j * 256;
        *(u32x4*)(buf + ((s * 16) ^ (((s >> 5) & 7) << 4))) = R[j];
    }
}

__device__ __forceinline__ void computeQ(const char* hbuf, const char* Ws, int q,
        int mh, int kg, int lrow, int quad, int swz, f32x4 (&acc)[2][2]) {
#pragma unroll
    for (int i = 0; i < 4; i++) {
        int kl = kg * 128 + i * 32 + quad * 8;     // k within quarter
        int kgl = q * 256 + kl;                    // global k
        bf16x8 a0 = *(const bf16x8*)(hbuf + (((mh + lrow) * 512 + kl * 2) ^ swz));
        bf16x8 a1 = *(const bf16x8*)(hbuf + (((mh + 16 + lrow) * 512 + kl * 2) ^ swz));
        bf16x8 b0 = *(const bf16x8*)(Ws + ((lrow * 2048 + kgl * 2) ^ swz));
        bf16x8 b1 = *(const bf16x8*)(Ws + (((lrow + 16) * 2048 + kgl * 2) ^ swz));
        acc[0][0] = __builtin_amdgcn_mfma_f32_16x16x32_bf16(a0, b0, acc[0][0], 0, 0, 0);
        acc[0][1] = __builtin_amdgcn_mfma_f32_16x16x32_bf16(a0, b1, acc[0][1], 0, 0, 0);
        acc[1][0] = __builtin_amdgcn_mfma_f32_16x16x32_bf16(a1, b0, acc[1][0], 0, 0, 0);
        acc[1][1] = __builtin_amdgcn_mfma_f32_16x16x32_bf16(a1, b1, acc[1][1], 0, 0, 0);
    }
}

__global__ __launch_bounds__(256, 1) void lstm_fused(
    const ushort_t* __restrict__ WtH,   // bf16 [4][1024 n][1024 k]
    const ushort_t* __restrict__ WtX,   // bf16 [4][1024 n][1024 k]
    const ushort_t* __restrict__ Gc,    // gates for THIS chunk [2048 m][4096 n']
    ushort_t* __restrict__ Gn,          // gates for NEXT chunk (written by gemm half)
    const float* __restrict__ input_,   // full input [512][64][1024]
    Ptr4 biases,
    const float* __restrict__ ret,      // fp32 [1024]
    float* __restrict__ cf_g,           // fp32 chunk-boundary state
    float* __restrict__ hf_g,           // fp32 chunk-boundary state
    ushort_t* __restrict__ hb0,         // bf16 h ping
    ushort_t* __restrict__ hb1,         // bf16 h pong
    float* __restrict__ out,            // d_out fp32
    unsigned* __restrict__ flags,       // [NWG] barrier flags (monotonic)
    int c)                              // chunk index
{
    extern __shared__ char smem[];

    if (blockIdx.x >= NWG) {
        // ================= gemm half: next chunk's gates =================
        if (c >= NCHUNK - 1) return;
        ushort_t* As = (ushort_t*)smem;
        ushort_t* Bs = (ushort_t*)(smem + 128 * LDK * 2);
        const float* A = input_ + (size_t)(c + 1) * MCH * 1024;
        int t = threadIdx.x;
#pragma unroll 1
        for (int tile = 0; tile < 4; tile++) {
            int tileid = (blockIdx.x - NWG) * 4 + tile;
            int n0 = (tileid & 31) * 128;
            int m0 = (tileid >> 5) * 128;
            gemm_tile(A, WtX, biases, Gn, As, Bs, n0, m0, t);
        }
        return;
    }

    // ================= recurrence half (R2-verified body) =================
    char* Ws  = smem;                                             // 64 KiB
    char* Hq0 = smem + WS_BYTES;                                  // 32 KiB
    char* Hq1 = smem + WS_BYTES + HQ_BYTES;                       // 32 KiB
    float* S  = (float*)(smem + WS_BYTES + 2 * HQ_BYTES);         // 18 KiB
    ushort_t* Gg = (ushort_t*)(smem + WS_BYTES + 2 * HQ_BYTES + S_BYTES);            // 4 KiB
    ushort_t* Hw = (ushort_t*)(smem + WS_BYTES + 2 * HQ_BYTES + S_BYTES + GG_BYTES); // 1 KiB

    const int tid = threadIdx.x;
    const int wg = blockIdx.x;
    const int u0 = wg * 8;
    const int wave = tid >> 6, lane = tid & 63;
    const int lrow = lane & 15, quad = lane >> 4;
    const int mh = (wave & 1) * 32;     // batch-half base (rows)
    const int kg = wave >> 1;           // k-half (0/1)
    const int swz = (lrow & 7) << 4;    // XOR swizzle term

    (void)wave; (void)lane;

    // ---- stage W_h slice into LDS once (swizzled dest), cached loads ----
#pragma unroll
    for (int rr = 0; rr < 16; rr++) {
        int idx = tid + rr * 256;          // 16B-slot id, 4096 slots
        int vc = idx >> 7;                 // 128 slots per 2048-B row
        int kb = (idx & 127) * 16;         // byte offset within row
        const ushort_t* src = WtH + (size_t)(vc >> 3) * 1048576
                                  + (size_t)(u0 + (vc & 7)) * 1024 + (kb >> 1);
        bf16x8 v = *(const bf16x8*)src;
        *(bf16x8*)(Ws + ((vc * 2048 + kb) ^ ((vc & 7) << 4))) = v;
    }

    // ---- persistent state in registers (2 (b,u) pairs per thread) ----
    float hf_r[2], cf_r[2], ret_r[2];
    int idx_r[2];
#pragma unroll
    for (int i = 0; i < 2; i++) {
        int lin = tid + i * 256;
        int b = lin >> 3, u = lin & 7;
        int idx = b * 1024 + u0 + u;
        idx_r[i] = idx;
        hf_r[i] = hf_g[idx];
        cf_r[i] = cf_g[idx];
        ret_r[i] = ret[u0 + u];
    }
    // pin state so no compiler-tracked VM loads remain outstanding in the loop
    asm volatile("" :: "v"(hf_r[0]), "v"(hf_r[1]), "v"(cf_r[0]), "v"(cf_r[1]),
                       "v"(ret_r[0]), "v"(ret_r[1]));
    __syncthreads();
    asm volatile("s_waitcnt vmcnt(0)" ::: "memory");

    const unsigned tbase = (unsigned)c * (unsigned)(CHUNK - 1);

#pragma unroll 1
    for (int tc = 0; tc < CHUNK; tc++) {
        const int t = c * CHUNK + tc;
        const ushort_t* hb_in = (tc & 1) ? hb1 : hb0;
        ushort_t* hb_out      = (tc & 1) ? hb0 : hb1;

        // gate-precompute prefetch — issued FIRST (oldest outstanding VM op)
        u32x4 gpre;
        {
            int b = tid >> 2, g = tid & 3;
            const ushort_t* gp = Gc + ((size_t)(tc * 64 + b)) * 4096 + g * 1024 + u0;
            GLOAD16_CACHED(gpre, gp);
        }

        // issue ALL FOUR quarters' coherent loads up-front (32 x 16B per thread)
        u32x4 R0[8], R1[8], R2[8], R3[8];
        qload(hb_in, 0, tid, R0);
        qload(hb_in, 1, tid, R1);
        qload(hb_in, 2, tid, R2);
        qload(hb_in, 3, tid, R3);
        // outstanding: gpre(1) + 32 loads. vmcnt(24) -> gpre+R0 complete.
        asm volatile("s_waitcnt vmcnt(24)"
            : "+v"(R0[0]), "+v"(R0[1]), "+v"(R0[2]), "+v"(R0[3]),
              "+v"(R0[4]), "+v"(R0[5]), "+v"(R0[6]), "+v"(R0[7]), "+v"(gpre) :: "memory");
        qwrite(Hq0, tid, R0);
        WGBAR();

        f32x4 acc[2][2] = {};
        computeQ(Hq0, Ws, 0, mh, kg, lrow, quad, swz, acc);
        WAITVM8(16, R1);
        qwrite(Hq1, tid, R1);
        WGBAR();

        computeQ(Hq1, Ws, 1, mh, kg, lrow, quad, swz, acc);
        WAITVM8(8, R2);
        qwrite(Hq0, tid, R2);
        WGBAR();

        computeQ(Hq0, Ws, 2, mh, kg, lrow, quad, swz, acc);
        WAITVM8(0, R3);
        qwrite(Hq1, tid, R3);
        WGBAR();

        computeQ(Hq1, Ws, 3, mh, kg, lrow, quad, swz, acc);

        // write kg-partial S (C/D layout: col = lane&15, row = quad*4 + r)
#pragma unroll
        for (int m = 0; m < 2; m++)
#pragma unroll
            for (int n = 0; n < 2; n++)
#pragma unroll
                for (int r = 0; r < 4; r++)
                    S[kg * 64 * S_STRIDE + (mh + m * 16 + quad * 4 + r) * S_STRIDE
                      + n * 16 + lrow] = acc[m][n][r];
        // park gate-precompute in LDS
        {
            int b = tid >> 2, g = tid & 3;
            *(u32x4*)&Gg[b * 32 + g * 8] = gpre;
        }
        WGBAR();

        // ---- elementwise LSTM + retention blend (register state) ----
        float hn_s[2];
#pragma unroll
        for (int i = 0; i < 2; i++) {
            int lin = tid + i * 256;
            int b = lin >> 3, u = lin & 7;
            int brow = b * S_STRIDE;
            float si = S[brow + u]      + S[64 * S_STRIDE + brow + u]      + bf2f(Gg[b * 32 + u]);
            float sf = S[brow + 8 + u]  + S[64 * S_STRIDE + brow + 8 + u]  + bf2f(Gg[b * 32 + 8 + u]);
            float so = S[brow + 16 + u] + S[64 * S_STRIDE + brow + 16 + u] + bf2f(Gg[b * 32 + 16 + u]);
            float sc = S[brow + 24 + u] + S[64 * S_STRIDE + brow + 24 + u] + bf2f(Gg[b * 32 + 24 + u]);
            float it = 1.f / (1.f + __expf(-si));
            float ft = 1.f / (1.f + __expf(-sf));
            float ot = 1.f / (1.f + __expf(-so));
            float gt = 1.f - 2.f / (__expf(2.f * sc) + 1.f);   // NaN-safe tanh
            float cn = cf_r[i] * ft + it * gt;
            float tcn = 1.f - 2.f / (__expf(2.f * cn) + 1.f);  // NaN-safe tanh
            float hl = ot * tcn;
            float rr = ret_r[i];
            float hn = rr * hf_r[i] + (1.f - rr) * hl;
            cf_r[i] = cn;
            hf_r[i] = hn;
            hn_s[i] = hn;
            Hw[lin] = f2bf(hn);                                // gather for coherent store
        }
        WGBAR();   // Hw visible

        // gathered coherent h-out store: wave 0 only (64 x 16B).
        if (tid < 64) {
            u32x4 v = *(const u32x4*)&Hw[tid * 8];
            ushort_t* dst = hb_out + (size_t)tid * 1024 + u0;
            GSTORE16_COH(dst, v);
            asm volatile("s_waitcnt vmcnt(0)" ::: "memory");
        }
        if (tc < CHUNK - 1 && tid == 0)
            __hip_atomic_store(&flags[wg], tbase + (unsigned)tc + 1u,
                               __ATOMIC_RELAXED, __HIP_MEMORY_SCOPE_AGENT);

        // out NT stores AFTER the release path (off the flag's critical path)
#pragma unroll
        for (int i = 0; i < 2; i++)
            __builtin_nontemporal_store(hn_s[i], &out[(size_t)t * 65536 + idx_r[i]]);

        // ---- grid barrier between steps (skip after last) ----
        if (tc < CHUNK - 1) {
            unsigned target = tbase + (unsigned)tc + 1u;
            if (tid < NWG)
                while (__hip_atomic_load(&flags[tid], __ATOMIC_RELAXED,
                                         __HIP_MEMORY_SCOPE_AGENT) < target) {}
            WGBAR();
            asm volatile("s_waitcnt vmcnt(0)" ::: "memory");  // drain polls + NT stores
        }
    }

    // ---- write back chunk-boundary state ----
#pragma unroll
    for (int i = 0; i < 2; i++) {
        hf_g[idx_r[i]] = hf_r[i];
        cf_g[idx_r[i]] = cf_r[i];
    }
}

// ---------------------------------------------------------------------------
// Epilogue: append h_T and c_T (fp32) to d_out
// ---------------------------------------------------------------------------
__global__ __launch_bounds__(256) void epilogue_k(
    const float* __restrict__ hf_final, const float* __restrict__ cf,
    float* __restrict__ out)
{
    int i = blockIdx.x * 256 + threadIdx.x;  // 65536
    out[OUTS_ELEMS + i] = hf_final[i];
    out[OUTS_ELEMS + 65536 + i] = cf[i];
}

// ---------------------------------------------------------------------------
extern "C" void kernel_launch(void* const* d_in, const int* in_sizes, int n_in,
                              void* d_out, int out_size, void* d_ws, size_t ws_size,
                              hipStream_t stream)
{
    const float* input_ = (const float*)d_in[0];
    const float* h0   = (const float*)d_in[1];
    const float* c0   = (const float*)d_in[2];
    const float* w_xi = (const float*)d_in[3];
    const float* w_xf = (const float*)d_in[4];
    const float* w_xo = (const float*)d_in[5];
    const float* w_xc = (const float*)d_in[6];
    const float* w_hi = (const float*)d_in[7];
    const float* w_hf = (const float*)d_in[8];
    const float* w_ho = (const float*)d_in[9];
    const float* w_hc = (const float*)d_in[10];
    const float* b_i  = (const float*)d_in[11];
    const float* b_f  = (const float*)d_in[12];
    const float* b_o  = (const float*)d_in[13];
    const float* b_c  = (const float*)d_in[14];
    const float* ret  = (const float*)d_in[15];

    // workspace carve (~49 MiB): double-buffered gate chunks
    ushort_t* wt_x   = (ushort_t*)d_ws;            // 4*1M bf16  (8 MiB)
    ushort_t* wt_h   = wt_x + 4ULL * 1048576;      // 4*1M bf16  (8 MiB)
    ushort_t* g0     = wt_h + 4ULL * 1048576;      // 2048*4096 bf16 (16 MiB)
    ushort_t* g1     = g0 + (size_t)MCH * 4096;    // 2048*4096 bf16 (16 MiB)
    float*  cf  = (float*)(g1 + (size_t)MCH * 4096);
    float*  hf0 = cf + 65536;
    float*  hf1 = hf0 + 65536;                     // (unused; carve kept stable)
    ushort_t* hb0 = (ushort_t*)(hf1 + 65536);
    ushort_t* hb1 = hb0 + 65536;
    unsigned* flags = (unsigned*)(hb1 + 65536);    // NWG barrier flags
    float* out = (float*)d_out;

    static bool attr_set = false;
    if (!attr_set) {
        hipFuncSetAttribute(reinterpret_cast<const void*>(lstm_fused),
                            hipFuncAttributeMaxDynamicSharedMemorySize, SMEM_BYTES);
        attr_set = true;
    }

    Ptr8 p8; p8.p[0] = w_xi; p8.p[1] = w_xf; p8.p[2] = w_xo; p8.p[3] = w_xc;
             p8.p[4] = w_hi; p8.p[5] = w_hf; p8.p[6] = w_ho; p8.p[7] = w_hc;
    transpose8<<<dim3(16, 16, 8), 256, 0, stream>>>(p8, wt_x);

    init_state<<<256, 256, 0, stream>>>(h0, c0, hf0, cf, hb0, flags);

    Ptr4 b4; b4.p[0] = b_i; b4.p[1] = b_f; b4.p[2] = b_o; b4.p[3] = b_c;

    // chunk 0 gates up-front; chunks 1..15 computed inside lstm_fused c-1
    chunk_gemm<<<dim3(32, 16), 256, 0, stream>>>(input_, wt_x, b4, g0);

    for (int chunk = 0; chunk < NCHUNK; chunk++) {
        const ushort_t* gcur = (chunk & 1) ? g1 : g0;
        ushort_t* gnext      = (chunk & 1) ? g0 : g1;
        lstm_fused<<<2 * NWG, 256, SMEM_BYTES, stream>>>(
            wt_h, wt_x, gcur, gnext, input_, b4, ret, cf, hf0,
            hb0, hb1, out, flags, chunk);
    }

    epilogue_k<<<256, 256, 0, stream>>>(hf0, cf, out);
}

// Round 7
// 3773.482 us; speedup vs baseline: 1.8091x; 1.1860x over previous
//
#include <hip/hip_runtime.h>

typedef unsigned short ushort_t;
typedef __bf16 bf16x8 __attribute__((ext_vector_type(8)));
typedef float f32x4 __attribute__((ext_vector_type(4)));
typedef unsigned int u32x4 __attribute__((ext_vector_type(4)));

#define T_STEPS 512
#define BATCH 64
#define HDIM 1024
#define CHUNK 32                 // steps per gate-precompute chunk
#define NCHUNK (T_STEPS / CHUNK) // 16
#define MCH (CHUNK * BATCH)      // 2048 rows per chunk GEMM
#define OUTS_ELEMS 33554432ULL
#define NWG 128                  // recurrence WGs; + 128 gemm WGs = 256 = #CUs

#define S_STRIDE 36              // padded fp32 row stride for S exchange

// ---- LDS carve for lstm_fused (dynamic) ----
#define WS_BYTES   65536                       // W_h slice: 32 vc x 1024 k bf16, swizzled
#define HQ_BYTES   32768                       // h quarter: 64 b x 256 k bf16, swizzled
#define S_BYTES    (2 * 64 * S_STRIDE * 4)     // 18432
#define GG_BYTES   (64 * 32 * 2)               // 4096
#define HW_BYTES   (64 * 8 * 2)                // 1024
#define SMEM_BYTES (WS_BYTES + 2 * HQ_BYTES + S_BYTES + GG_BYTES + HW_BYTES) // 154624

// ---- coherent (LLC-level, cross-XCD) access: sc0 sc1 bypass L1+L2 ----
#define GLOAD16_COH(dst, src) \
    asm volatile("global_load_dwordx4 %0, %1, off sc0 sc1" : "=v"(dst) : "v"(src) : "memory")
#define GLOAD16_CACHED(dst, src) \
    asm volatile("global_load_dwordx4 %0, %1, off" : "=v"(dst) : "v"(src) : "memory")
#define GSTORE16_COH(dst, val) \
    asm volatile("global_store_dwordx4 %0, %1, off sc0 sc1" :: "v"(dst), "v"(val) : "memory")
// counted vmcnt wait, register-tied so consumers can't be hoisted above it
#define WAITVM8(N, R) \
    asm volatile("s_waitcnt vmcnt(" #N ")" \
        : "+v"(R[0]), "+v"(R[1]), "+v"(R[2]), "+v"(R[3]), \
          "+v"(R[4]), "+v"(R[5]), "+v"(R[6]), "+v"(R[7]) :: "memory")
// raw workgroup barrier: LDS-visibility only, does NOT drain vmcnt
#define WGBAR() do { asm volatile("s_waitcnt lgkmcnt(0)" ::: "memory"); \
                     __builtin_amdgcn_s_barrier(); } while (0)

__device__ __forceinline__ ushort_t f2bf(float f) {
    union { unsigned int i; float f; } v;
    v.f = f;
    unsigned int x = v.i;
    unsigned int r = (x + 0x7FFFu + ((x >> 16) & 1u)) >> 16;
    return (ushort_t)r;
}

__device__ __forceinline__ float bf2f(ushort_t u) {
    union { unsigned int i; float f; } v;
    v.i = ((unsigned int)u) << 16;
    return v.f;
}

struct Ptr8 { const float* p[8]; };
struct Ptr4 { const float* p[4]; };

// ---------------------------------------------------------------------------
// Transpose+convert 8 fp32 weight matrices [1024 k][1024 n] -> bf16 [1024 n][1024 k]
// ---------------------------------------------------------------------------
__global__ __launch_bounds__(256) void transpose8(Ptr8 in, ushort_t* __restrict__ out) {
    __shared__ ushort_t tile[64][65];
    int z = blockIdx.z;
    const float* src = in.p[z];
    ushort_t* dst = out + (size_t)z * 1024 * 1024;
    int bx = blockIdx.x * 64;  // n base
    int by = blockIdx.y * 64;  // k base
    int t = threadIdx.x;
#pragma unroll
    for (int i = 0; i < 16; i++) {
        int lin = t + i * 256;
        int r = lin >> 6, c = lin & 63;
        tile[r][c] = f2bf(src[(size_t)(by + r) * 1024 + bx + c]);
    }
    __syncthreads();
#pragma unroll
    for (int i = 0; i < 16; i++) {
        int lin = t + i * 256;
        int r = lin >> 6, c = lin & 63;
        dst[(size_t)(bx + r) * 1024 + by + c] = tile[c][r];
    }
}

// ---------------------------------------------------------------------------
// Shared GEMM tile body (used by standalone chunk_gemm and the fused kernel's
// gemm half). G[m][n'] = A[m][:] @ Wt[n'][:] + bias.
// ---------------------------------------------------------------------------
#define BK 32
#define LDK 40

__device__ __forceinline__ void gemm_tile(
    const float* __restrict__ A, const ushort_t* __restrict__ Wt, Ptr4 biases,
    ushort_t* __restrict__ G, ushort_t* As, ushort_t* Bs, int n0, int m0, int t)
{
    int wave = t >> 6, lane = t & 63;
    int wm = (wave & 1) * 64, wn = (wave >> 1) * 64;
    int lrow = lane & 15, quad = lane >> 4;
    int lk = quad * 8;

    f32x4 acc[4][4] = {};

    for (int k0 = 0; k0 < 1024; k0 += BK) {
        __syncthreads();
#pragma unroll
        for (int i = 0; i < 4; i++) {
            int c = t + 256 * i;
            int r = c >> 3, kc = c & 7;
            const float4 v = *(const float4*)&A[(size_t)(m0 + r) * 1024 + k0 + kc * 4];
            ushort_t* d = &As[r * LDK + kc * 4];
            d[0] = f2bf(v.x); d[1] = f2bf(v.y); d[2] = f2bf(v.z); d[3] = f2bf(v.w);
        }
#pragma unroll
        for (int i = 0; i < 2; i++) {
            int c = t + 256 * i;
            int r = c >> 2, kc = c & 3;
            *(bf16x8*)&Bs[r * LDK + kc * 8] =
                *(const bf16x8*)&Wt[(size_t)(n0 + r) * 1024 + k0 + kc * 8];
        }
        __syncthreads();

        bf16x8 a[4], b[4];
#pragma unroll
        for (int i = 0; i < 4; i++)
            a[i] = *(const bf16x8*)&As[(wm + i * 16 + lrow) * LDK + lk];
#pragma unroll
        for (int j = 0; j < 4; j++)
            b[j] = *(const bf16x8*)&Bs[(wn + j * 16 + lrow) * LDK + lk];
#pragma unroll
        for (int i = 0; i < 4; i++)
#pragma unroll
            for (int j = 0; j < 4; j++)
                acc[i][j] = __builtin_amdgcn_mfma_f32_16x16x32_bf16(a[i], b[j], acc[i][j], 0, 0, 0);
    }

    int g = n0 >> 10;
    const float* bias = biases.p[g];
    int cg0 = (n0 & 1023) + wn;
#pragma unroll
    for (int j = 0; j < 4; j++) {
        int coln = n0 + wn + j * 16 + lrow;
        float bv = bias[cg0 + j * 16 + lrow];
#pragma unroll
        for (int i = 0; i < 4; i++) {
#pragma unroll
            for (int r = 0; r < 4; r++) {
                int rowm = m0 + wm + i * 16 + quad * 4 + r;
                G[(size_t)rowm * 4096 + coln] = f2bf(acc[i][j][r] + bv);
            }
        }
    }
}

__global__ __launch_bounds__(256) void chunk_gemm(
    const float* __restrict__ A,
    const ushort_t* __restrict__ Wt,
    Ptr4 biases,
    ushort_t* __restrict__ G)
{
    __shared__ ushort_t As[128 * LDK];
    __shared__ ushort_t Bs[128 * LDK];
    gemm_tile(A, Wt, biases, G, As, Bs, blockIdx.x * 128, blockIdx.y * 128, threadIdx.x);
}

// ---------------------------------------------------------------------------
// Init state + zero barrier counter (fresh per launch / graph replay)
// ---------------------------------------------------------------------------
__global__ __launch_bounds__(256) void init_state(
    const float* __restrict__ h0, const float* __restrict__ c0,
    float* __restrict__ hf, float* __restrict__ cf, ushort_t* __restrict__ hb,
    unsigned* __restrict__ flags)
{
    int i = blockIdx.x * 256 + threadIdx.x;  // 65536
    float h = h0[i];
    hf[i] = h;
    cf[i] = c0[i];
    hb[i] = f2bf(h);
    if (blockIdx.x == 0 && threadIdx.x < NWG) flags[threadIdx.x] = 0;
}

// ---------------------------------------------------------------------------
// Fused persistent kernel, 256 WGs (1/CU):
//   WGs 0..127   : per-chunk recurrence on Gc_cur (32 steps)
//   WGs 128..255 : next chunk's gate GEMM into Gc_next (4 tiles each)
// Grid barrier = SINGLE arrival counter (atomic add per WG, ONE polling lane
// per WG) — eliminates the 16K-lane coherent poll storm of the flag array.
// ---------------------------------------------------------------------------
__device__ __forceinline__ void qload(const ushort_t* __restrict__ hb_in, int q,
                                      int tid, u32x4 (&R)[8]) {
#pragma unroll
    for (int j = 0; j < 8; j++) {
        int s = tid + j * 256;
        const ushort_t* src = hb_in + (size_t)(s >> 5) * 1024 + q * 256 + ((s & 31) << 3);
        GLOAD16_COH(R[j], src);
    }
}

__device__ __forceinline__ void qwrite(char* buf, int tid, u32x4 (&R)[8]) {
#pragma unroll
    for (int j = 0; j < 8; j++) {
        int s = tid + j * 256;
        *(u32x4*)(buf + ((s * 16) ^ (((s >> 5) & 7) << 4))) = R[j];
    }
}

__device__ __forceinline__ void computeQ(const char* hbuf, const char* Ws, int q,
        int mh, int kg, int lrow, int quad, int swz, f32x4 (&acc)[2][2]) {
#pragma unroll
    for (int i = 0; i < 4; i++) {
        int kl = kg * 128 + i * 32 + quad * 8;     // k within quarter
        int kgl = q * 256 + kl;                    // global k
        bf16x8 a0 = *(const bf16x8*)(hbuf + (((mh + lrow) * 512 + kl * 2) ^ swz));
        bf16x8 a1 = *(const bf16x8*)(hbuf + (((mh + 16 + lrow) * 512 + kl * 2) ^ swz));
        bf16x8 b0 = *(const bf16x8*)(Ws + ((lrow * 2048 + kgl * 2) ^ swz));
        bf16x8 b1 = *(const bf16x8*)(Ws + (((lrow + 16) * 2048 + kgl * 2) ^ swz));
        acc[0][0] = __builtin_amdgcn_mfma_f32_16x16x32_bf16(a0, b0, acc[0][0], 0, 0, 0);
        acc[0][1] = __builtin_amdgcn_mfma_f32_16x16x32_bf16(a0, b1, acc[0][1], 0, 0, 0);
        acc[1][0] = __builtin_amdgcn_mfma_f32_16x16x32_bf16(a1, b0, acc[1][0], 0, 0, 0);
        acc[1][1] = __builtin_amdgcn_mfma_f32_16x16x32_bf16(a1, b1, acc[1][1], 0, 0, 0);
    }
}

__global__ __launch_bounds__(256, 1) void lstm_fused(
    const ushort_t* __restrict__ WtH,   // bf16 [4][1024 n][1024 k]
    const ushort_t* __restrict__ WtX,   // bf16 [4][1024 n][1024 k]
    const ushort_t* __restrict__ Gc,    // gates for THIS chunk [2048 m][4096 n']
    ushort_t* __restrict__ Gn,          // gates for NEXT chunk (written by gemm half)
    const float* __restrict__ input_,   // full input [512][64][1024]
    Ptr4 biases,
    const float* __restrict__ ret,      // fp32 [1024]
    float* __restrict__ cf_g,           // fp32 chunk-boundary state
    float* __restrict__ hf_g,           // fp32 chunk-boundary state
    ushort_t* __restrict__ hb0,         // bf16 h ping
    ushort_t* __restrict__ hb1,         // bf16 h pong
    float* __restrict__ out,            // d_out fp32
    unsigned* __restrict__ flags,       // [0] = arrival counter (monotonic)
    int c)                              // chunk index
{
    extern __shared__ char smem[];

    if (blockIdx.x >= NWG) {
        // ================= gemm half: next chunk's gates =================
        if (c >= NCHUNK - 1) return;
        ushort_t* As = (ushort_t*)smem;
        ushort_t* Bs = (ushort_t*)(smem + 128 * LDK * 2);
        const float* A = input_ + (size_t)(c + 1) * MCH * 1024;
        int t = threadIdx.x;
#pragma unroll 1
        for (int tile = 0; tile < 4; tile++) {
            int tileid = (blockIdx.x - NWG) * 4 + tile;
            int n0 = (tileid & 31) * 128;
            int m0 = (tileid >> 5) * 128;
            gemm_tile(A, WtX, biases, Gn, As, Bs, n0, m0, t);
        }
        return;
    }

    // ================= recurrence half =================
    char* Ws  = smem;                                             // 64 KiB
    char* Hq0 = smem + WS_BYTES;                                  // 32 KiB
    char* Hq1 = smem + WS_BYTES + HQ_BYTES;                       // 32 KiB
    float* S  = (float*)(smem + WS_BYTES + 2 * HQ_BYTES);         // 18 KiB
    ushort_t* Gg = (ushort_t*)(smem + WS_BYTES + 2 * HQ_BYTES + S_BYTES);            // 4 KiB
    ushort_t* Hw = (ushort_t*)(smem + WS_BYTES + 2 * HQ_BYTES + S_BYTES + GG_BYTES); // 1 KiB

    const int tid = threadIdx.x;
    const int wg = blockIdx.x;
    const int u0 = wg * 8;
    const int wave = tid >> 6, lane = tid & 63;
    const int lrow = lane & 15, quad = lane >> 4;
    const int mh = (wave & 1) * 32;     // batch-half base (rows)
    const int kg = wave >> 1;           // k-half (0/1)
    const int swz = (lrow & 7) << 4;    // XOR swizzle term

    (void)wave; (void)lane;

    // ---- stage W_h slice into LDS once (swizzled dest), cached loads ----
#pragma unroll
    for (int rr = 0; rr < 16; rr++) {
        int idx = tid + rr * 256;          // 16B-slot id, 4096 slots
        int vc = idx >> 7;                 // 128 slots per 2048-B row
        int kb = (idx & 127) * 16;         // byte offset within row
        const ushort_t* src = WtH + (size_t)(vc >> 3) * 1048576
                                  + (size_t)(u0 + (vc & 7)) * 1024 + (kb >> 1);
        bf16x8 v = *(const bf16x8*)src;
        *(bf16x8*)(Ws + ((vc * 2048 + kb) ^ ((vc & 7) << 4))) = v;
    }

    // ---- persistent state in registers (2 (b,u) pairs per thread) ----
    float hf_r[2], cf_r[2], ret_r[2];
    int idx_r[2];
#pragma unroll
    for (int i = 0; i < 2; i++) {
        int lin = tid + i * 256;
        int b = lin >> 3, u = lin & 7;
        int idx = b * 1024 + u0 + u;
        idx_r[i] = idx;
        hf_r[i] = hf_g[idx];
        cf_r[i] = cf_g[idx];
        ret_r[i] = ret[u0 + u];
    }
    // pin state so no compiler-tracked VM loads remain outstanding in the loop
    asm volatile("" :: "v"(hf_r[0]), "v"(hf_r[1]), "v"(cf_r[0]), "v"(cf_r[1]),
                       "v"(ret_r[0]), "v"(ret_r[1]));
    __syncthreads();
    asm volatile("s_waitcnt vmcnt(0)" ::: "memory");

    const unsigned kbase = (unsigned)c * (unsigned)(CHUNK - 1);

#pragma unroll 1
    for (int tc = 0; tc < CHUNK; tc++) {
        const int t = c * CHUNK + tc;
        const ushort_t* hb_in = (tc & 1) ? hb1 : hb0;
        ushort_t* hb_out      = (tc & 1) ? hb0 : hb1;

        // gate-precompute prefetch — issued FIRST (oldest outstanding VM op)
        u32x4 gpre;
        {
            int b = tid >> 2, g = tid & 3;
            const ushort_t* gp = Gc + ((size_t)(tc * 64 + b)) * 4096 + g * 1024 + u0;
            GLOAD16_CACHED(gpre, gp);
        }

        // issue ALL FOUR quarters' coherent loads up-front (32 x 16B per thread)
        u32x4 R0[8], R1[8], R2[8], R3[8];
        qload(hb_in, 0, tid, R0);
        qload(hb_in, 1, tid, R1);
        qload(hb_in, 2, tid, R2);
        qload(hb_in, 3, tid, R3);
        // outstanding: gpre(1) + 32 loads. vmcnt(24) -> gpre+R0 complete.
        asm volatile("s_waitcnt vmcnt(24)"
            : "+v"(R0[0]), "+v"(R0[1]), "+v"(R0[2]), "+v"(R0[3]),
              "+v"(R0[4]), "+v"(R0[5]), "+v"(R0[6]), "+v"(R0[7]), "+v"(gpre) :: "memory");
        qwrite(Hq0, tid, R0);
        WGBAR();

        f32x4 acc[2][2] = {};
        computeQ(Hq0, Ws, 0, mh, kg, lrow, quad, swz, acc);
        WAITVM8(16, R1);
        qwrite(Hq1, tid, R1);
        WGBAR();

        computeQ(Hq1, Ws, 1, mh, kg, lrow, quad, swz, acc);
        WAITVM8(8, R2);
        qwrite(Hq0, tid, R2);
        WGBAR();

        computeQ(Hq0, Ws, 2, mh, kg, lrow, quad, swz, acc);
        WAITVM8(0, R3);
        qwrite(Hq1, tid, R3);
        WGBAR();

        computeQ(Hq1, Ws, 3, mh, kg, lrow, quad, swz, acc);

        // write kg-partial S (C/D layout: col = lane&15, row = quad*4 + r)
#pragma unroll
        for (int m = 0; m < 2; m++)
#pragma unroll
            for (int n = 0; n < 2; n++)
#pragma unroll
                for (int r = 0; r < 4; r++)
                    S[kg * 64 * S_STRIDE + (mh + m * 16 + quad * 4 + r) * S_STRIDE
                      + n * 16 + lrow] = acc[m][n][r];
        // park gate-precompute in LDS
        {
            int b = tid >> 2, g = tid & 3;
            *(u32x4*)&Gg[b * 32 + g * 8] = gpre;
        }
        WGBAR();

        // ---- elementwise LSTM + retention blend (register state) ----
        float hn_s[2];
#pragma unroll
        for (int i = 0; i < 2; i++) {
            int lin = tid + i * 256;
            int b = lin >> 3, u = lin & 7;
            int brow = b * S_STRIDE;
            float si = S[brow + u]      + S[64 * S_STRIDE + brow + u]      + bf2f(Gg[b * 32 + u]);
            float sf = S[brow + 8 + u]  + S[64 * S_STRIDE + brow + 8 + u]  + bf2f(Gg[b * 32 + 8 + u]);
            float so = S[brow + 16 + u] + S[64 * S_STRIDE + brow + 16 + u] + bf2f(Gg[b * 32 + 16 + u]);
            float sc = S[brow + 24 + u] + S[64 * S_STRIDE + brow + 24 + u] + bf2f(Gg[b * 32 + 24 + u]);
            float it = 1.f / (1.f + __expf(-si));
            float ft = 1.f / (1.f + __expf(-sf));
            float ot = 1.f / (1.f + __expf(-so));
            float gt = 1.f - 2.f / (__expf(2.f * sc) + 1.f);   // NaN-safe tanh
            float cn = cf_r[i] * ft + it * gt;
            float tcn = 1.f - 2.f / (__expf(2.f * cn) + 1.f);  // NaN-safe tanh
            float hl = ot * tcn;
            float rr = ret_r[i];
            float hn = rr * hf_r[i] + (1.f - rr) * hl;
            cf_r[i] = cn;
            hf_r[i] = hn;
            hn_s[i] = hn;
            Hw[lin] = f2bf(hn);                                // gather for coherent store
        }
        WGBAR();   // Hw visible

        // gathered coherent h-out store: wave 0 only (64 x 16B).
        if (tid < 64) {
            u32x4 v = *(const u32x4*)&Hw[tid * 8];
            ushort_t* dst = hb_out + (size_t)tid * 1024 + u0;
            GSTORE16_COH(dst, v);
            asm volatile("s_waitcnt vmcnt(0)" ::: "memory");
        }
        // arrive: one atomic add per WG (after h stores acked at LLC)
        if (tc < CHUNK - 1 && tid == 0)
            __hip_atomic_fetch_add(flags, 1u, __ATOMIC_RELAXED,
                                   __HIP_MEMORY_SCOPE_AGENT);

        // out NT stores AFTER the release path (off the flag's critical path)
#pragma unroll
        for (int i = 0; i < 2; i++)
            __builtin_nontemporal_store(hn_s[i], &out[(size_t)t * 65536 + idx_r[i]]);

        // ---- grid barrier: ONE polling lane per WG on the single counter ----
        if (tc < CHUNK - 1) {
            unsigned target = (unsigned)NWG * (kbase + (unsigned)tc + 1u);
            if (tid == 0)
                while (__hip_atomic_load(flags, __ATOMIC_RELAXED,
                                         __HIP_MEMORY_SCOPE_AGENT) < target) {}
            WGBAR();
            asm volatile("s_waitcnt vmcnt(0)" ::: "memory");  // drain NT stores + poll
        }
    }

    // ---- write back chunk-boundary state ----
#pragma unroll
    for (int i = 0; i < 2; i++) {
        hf_g[idx_r[i]] = hf_r[i];
        cf_g[idx_r[i]] = cf_r[i];
    }
}

// ---------------------------------------------------------------------------
// Epilogue: append h_T and c_T (fp32) to d_out
// ---------------------------------------------------------------------------
__global__ __launch_bounds__(256) void epilogue_k(
    const float* __restrict__ hf_final, const float* __restrict__ cf,
    float* __restrict__ out)
{
    int i = blockIdx.x * 256 + threadIdx.x;  // 65536
    out[OUTS_ELEMS + i] = hf_final[i];
    out[OUTS_ELEMS + 65536 + i] = cf[i];
}

// ---------------------------------------------------------------------------
extern "C" void kernel_launch(void* const* d_in, const int* in_sizes, int n_in,
                              void* d_out, int out_size, void* d_ws, size_t ws_size,
                              hipStream_t stream)
{
    const float* input_ = (const float*)d_in[0];
    const float* h0   = (const float*)d_in[1];
    const float* c0   = (const float*)d_in[2];
    const float* w_xi = (const float*)d_in[3];
    const float* w_xf = (const float*)d_in[4];
    const float* w_xo = (const float*)d_in[5];
    const float* w_xc = (const float*)d_in[6];
    const float* w_hi = (const float*)d_in[7];
    const float* w_hf = (const float*)d_in[8];
    const float* w_ho = (const float*)d_in[9];
    const float* w_hc = (const float*)d_in[10];
    const float* b_i  = (const float*)d_in[11];
    const float* b_f  = (const float*)d_in[12];
    const float* b_o  = (const float*)d_in[13];
    const float* b_c  = (const float*)d_in[14];
    const float* ret  = (const float*)d_in[15];

    // workspace carve (~49 MiB): double-buffered gate chunks
    ushort_t* wt_x   = (ushort_t*)d_ws;            // 4*1M bf16  (8 MiB)
    ushort_t* wt_h   = wt_x + 4ULL * 1048576;      // 4*1M bf16  (8 MiB)
    ushort_t* g0     = wt_h + 4ULL * 1048576;      // 2048*4096 bf16 (16 MiB)
    ushort_t* g1     = g0 + (size_t)MCH * 4096;    // 2048*4096 bf16 (16 MiB)
    float*  cf  = (float*)(g1 + (size_t)MCH * 4096);
    float*  hf0 = cf + 65536;
    float*  hf1 = hf0 + 65536;                     // (unused; carve kept stable)
    ushort_t* hb0 = (ushort_t*)(hf1 + 65536);
    ushort_t* hb1 = hb0 + 65536;
    unsigned* flags = (unsigned*)(hb1 + 65536);    // [0] arrival counter
    float* out = (float*)d_out;

    static bool attr_set = false;
    if (!attr_set) {
        hipFuncSetAttribute(reinterpret_cast<const void*>(lstm_fused),
                            hipFuncAttributeMaxDynamicSharedMemorySize, SMEM_BYTES);
        attr_set = true;
    }

    Ptr8 p8; p8.p[0] = w_xi; p8.p[1] = w_xf; p8.p[2] = w_xo; p8.p[3] = w_xc;
             p8.p[4] = w_hi; p8.p[5] = w_hf; p8.p[6] = w_ho; p8.p[7] = w_hc;
    transpose8<<<dim3(16, 16, 8), 256, 0, stream>>>(p8, wt_x);

    init_state<<<256, 256, 0, stream>>>(h0, c0, hf0, cf, hb0, flags);

    Ptr4 b4; b4.p[0] = b_i; b4.p[1] = b_f; b4.p[2] = b_o; b4.p[3] = b_c;

    // chunk 0 gates up-front; chunks 1..15 computed inside lstm_fused c-1
    chunk_gemm<<<dim3(32, 16), 256, 0, stream>>>(input_, wt_x, b4, g0);

    for (int chunk = 0; chunk < NCHUNK; chunk++) {
        const ushort_t* gcur = (chunk & 1) ? g1 : g0;
        ushort_t* gnext      = (chunk & 1) ? g0 : g1;
        lstm_fused<<<2 * NWG, 256, SMEM_BYTES, stream>>>(
            wt_h, wt_x, gcur, gnext, input_, b4, ret, cf, hf0,
            hb0, hb1, out, flags, chunk);
    }

    epilogue_k<<<256, 256, 0, stream>>>(hf0, cf, out);
}

// Round 8
// 3333.212 us; speedup vs baseline: 2.0481x; 1.1321x over previous
//
#include <hip/hip_runtime.h>

typedef unsigned short ushort_t;
typedef __bf16 bf16x8 __attribute__((ext_vector_type(8)));
typedef float f32x4 __attribute__((ext_vector_type(4)));
typedef unsigned int u32x4 __attribute__((ext_vector_type(4)));

#define T_STEPS 512
#define BATCH 64
#define HDIM 1024
#define CHUNK 32                 // steps per gate-precompute chunk
#define NCHUNK (T_STEPS / CHUNK) // 16
#define MCH (CHUNK * BATCH)      // 2048 rows per chunk GEMM
#define OUTS_ELEMS 33554432ULL
#define NWG 128                  // recurrence WGs; + 128 gemm WGs = 256 = #CUs

#define S_STRIDE 36              // padded fp32 row stride for S exchange

// ---- LDS carve for lstm_fused (dynamic) ----
#define WS_BYTES   65536                       // W_h slice: 32 vc x 1024 k bf16, swizzled
#define HQ_BYTES   32768                       // h quarter: 64 b x 256 k bf16, swizzled
#define S_BYTES    (2 * 64 * S_STRIDE * 4)     // 18432
#define GG_BYTES   (64 * 32 * 2)               // 4096
#define HW_BYTES   (64 * 8 * 2)                // 1024
#define SMEM_BYTES (WS_BYTES + 2 * HQ_BYTES + S_BYTES + GG_BYTES + HW_BYTES) // 154624

// ---- coherent (LLC-level, cross-XCD) access: sc0 sc1 bypass L1+L2 ----
#define GLOAD16_COH(dst, src) \
    asm volatile("global_load_dwordx4 %0, %1, off sc0 sc1" : "=v"(dst) : "v"(src) : "memory")
#define GLOAD16_CACHED(dst, src) \
    asm volatile("global_load_dwordx4 %0, %1, off" : "=v"(dst) : "v"(src) : "memory")
#define GSTORE16_COH(dst, val) \
    asm volatile("global_store_dwordx4 %0, %1, off sc0 sc1" :: "v"(dst), "v"(val) : "memory")
// counted vmcnt wait, register-tied so consumers can't be hoisted above it
#define WAITVM8(N, R) \
    asm volatile("s_waitcnt vmcnt(" #N ")" \
        : "+v"(R[0]), "+v"(R[1]), "+v"(R[2]), "+v"(R[3]), \
          "+v"(R[4]), "+v"(R[5]), "+v"(R[6]), "+v"(R[7]) :: "memory")
// raw workgroup barrier: LDS-visibility only, does NOT drain vmcnt
#define WGBAR() do { asm volatile("s_waitcnt lgkmcnt(0)" ::: "memory"); \
                     __builtin_amdgcn_s_barrier(); } while (0)

__device__ __forceinline__ ushort_t f2bf(float f) {
    union { unsigned int i; float f; } v;
    v.f = f;
    unsigned int x = v.i;
    unsigned int r = (x + 0x7FFFu + ((x >> 16) & 1u)) >> 16;
    return (ushort_t)r;
}

__device__ __forceinline__ float bf2f(ushort_t u) {
    union { unsigned int i; float f; } v;
    v.i = ((unsigned int)u) << 16;
    return v.f;
}

struct Ptr8 { const float* p[8]; };
struct Ptr4 { const float* p[4]; };

// ---------------------------------------------------------------------------
// Transpose+convert 8 fp32 weight matrices [1024 k][1024 n] -> bf16 [1024 n][1024 k]
// ---------------------------------------------------------------------------
__global__ __launch_bounds__(256) void transpose8(Ptr8 in, ushort_t* __restrict__ out) {
    __shared__ ushort_t tile[64][65];
    int z = blockIdx.z;
    const float* src = in.p[z];
    ushort_t* dst = out + (size_t)z * 1024 * 1024;
    int bx = blockIdx.x * 64;  // n base
    int by = blockIdx.y * 64;  // k base
    int t = threadIdx.x;
#pragma unroll
    for (int i = 0; i < 16; i++) {
        int lin = t + i * 256;
        int r = lin >> 6, c = lin & 63;
        tile[r][c] = f2bf(src[(size_t)(by + r) * 1024 + bx + c]);
    }
    __syncthreads();
#pragma unroll
    for (int i = 0; i < 16; i++) {
        int lin = t + i * 256;
        int r = lin >> 6, c = lin & 63;
        dst[(size_t)(bx + r) * 1024 + by + c] = tile[c][r];
    }
}

// ---------------------------------------------------------------------------
// Shared GEMM tile body (used by standalone chunk_gemm and the fused kernel's
// gemm half). G[m][n'] = A[m][:] @ Wt[n'][:] + bias.
// ---------------------------------------------------------------------------
#define BK 32
#define LDK 40

__device__ __forceinline__ void gemm_tile(
    const float* __restrict__ A, const ushort_t* __restrict__ Wt, Ptr4 biases,
    ushort_t* __restrict__ G, ushort_t* As, ushort_t* Bs, int n0, int m0, int t)
{
    int wave = t >> 6, lane = t & 63;
    int wm = (wave & 1) * 64, wn = (wave >> 1) * 64;
    int lrow = lane & 15, quad = lane >> 4;
    int lk = quad * 8;

    f32x4 acc[4][4] = {};

    for (int k0 = 0; k0 < 1024; k0 += BK) {
        __syncthreads();
#pragma unroll
        for (int i = 0; i < 4; i++) {
            int c = t + 256 * i;
            int r = c >> 3, kc = c & 7;
            const float4 v = *(const float4*)&A[(size_t)(m0 + r) * 1024 + k0 + kc * 4];
            ushort_t* d = &As[r * LDK + kc * 4];
            d[0] = f2bf(v.x); d[1] = f2bf(v.y); d[2] = f2bf(v.z); d[3] = f2bf(v.w);
        }
#pragma unroll
        for (int i = 0; i < 2; i++) {
            int c = t + 256 * i;
            int r = c >> 2, kc = c & 3;
            *(bf16x8*)&Bs[r * LDK + kc * 8] =
                *(const bf16x8*)&Wt[(size_t)(n0 + r) * 1024 + k0 + kc * 8];
        }
        __syncthreads();

        bf16x8 a[4], b[4];
#pragma unroll
        for (int i = 0; i < 4; i++)
            a[i] = *(const bf16x8*)&As[(wm + i * 16 + lrow) * LDK + lk];
#pragma unroll
        for (int j = 0; j < 4; j++)
            b[j] = *(const bf16x8*)&Bs[(wn + j * 16 + lrow) * LDK + lk];
#pragma unroll
        for (int i = 0; i < 4; i++)
#pragma unroll
            for (int j = 0; j < 4; j++)
                acc[i][j] = __builtin_amdgcn_mfma_f32_16x16x32_bf16(a[i], b[j], acc[i][j], 0, 0, 0);
    }

    int g = n0 >> 10;
    const float* bias = biases.p[g];
    int cg0 = (n0 & 1023) + wn;
#pragma unroll
    for (int j = 0; j < 4; j++) {
        int coln = n0 + wn + j * 16 + lrow;
        float bv = bias[cg0 + j * 16 + lrow];
#pragma unroll
        for (int i = 0; i < 4; i++) {
#pragma unroll
            for (int r = 0; r < 4; r++) {
                int rowm = m0 + wm + i * 16 + quad * 4 + r;
                G[(size_t)rowm * 4096 + coln] = f2bf(acc[i][j][r] + bv);
            }
        }
    }
}

__global__ __launch_bounds__(256) void chunk_gemm(
    const float* __restrict__ A,
    const ushort_t* __restrict__ Wt,
    Ptr4 biases,
    ushort_t* __restrict__ G)
{
    __shared__ ushort_t As[128 * LDK];
    __shared__ ushort_t Bs[128 * LDK];
    gemm_tile(A, Wt, biases, G, As, Bs, blockIdx.x * 128, blockIdx.y * 128, threadIdx.x);
}

// ---------------------------------------------------------------------------
// Init state + zero barrier counters (fresh per launch / graph replay)
// ---------------------------------------------------------------------------
__global__ __launch_bounds__(256) void init_state(
    const float* __restrict__ h0, const float* __restrict__ c0,
    float* __restrict__ hf, float* __restrict__ cf, ushort_t* __restrict__ hb,
    unsigned* __restrict__ flags)
{
    int i = blockIdx.x * 256 + threadIdx.x;  // 65536
    float h = h0[i];
    hf[i] = h;
    cf[i] = c0[i];
    hb[i] = f2bf(h);
    if (blockIdx.x == 0) flags[threadIdx.x] = 0;   // 8 counters live at [k*32]
}

// ---------------------------------------------------------------------------
// Fused persistent kernel, 256 WGs (1/CU):
//   WGs 0..127   : per-chunk recurrence on Gc_cur (32 steps)
//   WGs 128..255 : next chunk's gate GEMM into Gc_next (4 tiles each)
// Grid barrier = 8 arrival counters (wg&7, each on its own 128-B line):
// 16-way atomic serialization per line (vs 128-way single-counter), polled by
// wave0 (lane i -> counter i&7, exit on __all).
// ---------------------------------------------------------------------------
__device__ __forceinline__ void qload(const ushort_t* __restrict__ hb_in, int q,
                                      int tid, u32x4 (&R)[8]) {
#pragma unroll
    for (int j = 0; j < 8; j++) {
        int s = tid + j * 256;
        const ushort_t* src = hb_in + (size_t)(s >> 5) * 1024 + q * 256 + ((s & 31) << 3);
        GLOAD16_COH(R[j], src);
    }
}

__device__ __forceinline__ void qwrite(char* buf, int tid, u32x4 (&R)[8]) {
#pragma unroll
    for (int j = 0; j < 8; j++) {
        int s = tid + j * 256;
        *(u32x4*)(buf + ((s * 16) ^ (((s >> 5) & 7) << 4))) = R[j];
    }
}

__device__ __forceinline__ void computeQ(const char* hbuf, const char* Ws, int q,
        int mh, int kg, int lrow, int quad, int swz, f32x4 (&acc)[2][2]) {
#pragma unroll
    for (int i = 0; i < 4; i++) {
        int kl = kg * 128 + i * 32 + quad * 8;     // k within quarter
        int kgl = q * 256 + kl;                    // global k
        bf16x8 a0 = *(const bf16x8*)(hbuf + (((mh + lrow) * 512 + kl * 2) ^ swz));
        bf16x8 a1 = *(const bf16x8*)(hbuf + (((mh + 16 + lrow) * 512 + kl * 2) ^ swz));
        bf16x8 b0 = *(const bf16x8*)(Ws + ((lrow * 2048 + kgl * 2) ^ swz));
        bf16x8 b1 = *(const bf16x8*)(Ws + (((lrow + 16) * 2048 + kgl * 2) ^ swz));
        acc[0][0] = __builtin_amdgcn_mfma_f32_16x16x32_bf16(a0, b0, acc[0][0], 0, 0, 0);
        acc[0][1] = __builtin_amdgcn_mfma_f32_16x16x32_bf16(a0, b1, acc[0][1], 0, 0, 0);
        acc[1][0] = __builtin_amdgcn_mfma_f32_16x16x32_bf16(a1, b0, acc[1][0], 0, 0, 0);
        acc[1][1] = __builtin_amdgcn_mfma_f32_16x16x32_bf16(a1, b1, acc[1][1], 0, 0, 0);
    }
}

__global__ __launch_bounds__(256, 1) void lstm_fused(
    const ushort_t* __restrict__ WtH,   // bf16 [4][1024 n][1024 k]
    const ushort_t* __restrict__ WtX,   // bf16 [4][1024 n][1024 k]
    const ushort_t* __restrict__ Gc,    // gates for THIS chunk [2048 m][4096 n']
    ushort_t* __restrict__ Gn,          // gates for NEXT chunk (written by gemm half)
    const float* __restrict__ input_,   // full input [512][64][1024]
    Ptr4 biases,
    const float* __restrict__ ret,      // fp32 [1024]
    float* __restrict__ cf_g,           // fp32 chunk-boundary state
    float* __restrict__ hf_g,           // fp32 chunk-boundary state
    ushort_t* __restrict__ hb0,         // bf16 h ping
    ushort_t* __restrict__ hb1,         // bf16 h pong
    float* __restrict__ out,            // d_out fp32
    unsigned* __restrict__ flags,       // 8 counters at [k*32] (128-B apart)
    int c)                              // chunk index
{
    extern __shared__ char smem[];

    if (blockIdx.x >= NWG) {
        // ================= gemm half: next chunk's gates =================
        if (c >= NCHUNK - 1) return;
        ushort_t* As = (ushort_t*)smem;
        ushort_t* Bs = (ushort_t*)(smem + 128 * LDK * 2);
        const float* A = input_ + (size_t)(c + 1) * MCH * 1024;
        int t = threadIdx.x;
#pragma unroll 1
        for (int tile = 0; tile < 4; tile++) {
            int tileid = (blockIdx.x - NWG) * 4 + tile;
            int n0 = (tileid & 31) * 128;
            int m0 = (tileid >> 5) * 128;
            gemm_tile(A, WtX, biases, Gn, As, Bs, n0, m0, t);
        }
        return;
    }

    // ================= recurrence half =================
    char* Ws  = smem;                                             // 64 KiB
    char* Hq0 = smem + WS_BYTES;                                  // 32 KiB
    char* Hq1 = smem + WS_BYTES + HQ_BYTES;                       // 32 KiB
    float* S  = (float*)(smem + WS_BYTES + 2 * HQ_BYTES);         // 18 KiB
    ushort_t* Gg = (ushort_t*)(smem + WS_BYTES + 2 * HQ_BYTES + S_BYTES);            // 4 KiB
    ushort_t* Hw = (ushort_t*)(smem + WS_BYTES + 2 * HQ_BYTES + S_BYTES + GG_BYTES); // 1 KiB

    const int tid = threadIdx.x;
    const int wg = blockIdx.x;
    const int u0 = wg * 8;
    const int wave = tid >> 6, lane = tid & 63;
    const int lrow = lane & 15, quad = lane >> 4;
    const int mh = (wave & 1) * 32;     // batch-half base (rows)
    const int kg = wave >> 1;           // k-half (0/1)
    const int swz = (lrow & 7) << 4;    // XOR swizzle term

    (void)wave; (void)lane;

    // ---- stage W_h slice into LDS once (swizzled dest), cached loads ----
#pragma unroll
    for (int rr = 0; rr < 16; rr++) {
        int idx = tid + rr * 256;          // 16B-slot id, 4096 slots
        int vc = idx >> 7;                 // 128 slots per 2048-B row
        int kb = (idx & 127) * 16;         // byte offset within row
        const ushort_t* src = WtH + (size_t)(vc >> 3) * 1048576
                                  + (size_t)(u0 + (vc & 7)) * 1024 + (kb >> 1);
        bf16x8 v = *(const bf16x8*)src;
        *(bf16x8*)(Ws + ((vc * 2048 + kb) ^ ((vc & 7) << 4))) = v;
    }

    // ---- persistent state in registers (2 (b,u) pairs per thread) ----
    float hf_r[2], cf_r[2], ret_r[2];
    int idx_r[2];
#pragma unroll
    for (int i = 0; i < 2; i++) {
        int lin = tid + i * 256;
        int b = lin >> 3, u = lin & 7;
        int idx = b * 1024 + u0 + u;
        idx_r[i] = idx;
        hf_r[i] = hf_g[idx];
        cf_r[i] = cf_g[idx];
        ret_r[i] = ret[u0 + u];
    }
    // pin state so no compiler-tracked VM loads remain outstanding in the loop
    asm volatile("" :: "v"(hf_r[0]), "v"(hf_r[1]), "v"(cf_r[0]), "v"(cf_r[1]),
                       "v"(ret_r[0]), "v"(ret_r[1]));
    __syncthreads();
    asm volatile("s_waitcnt vmcnt(0)" ::: "memory");

    const unsigned kbase = (unsigned)c * (unsigned)(CHUNK - 1);

#pragma unroll 1
    for (int tc = 0; tc < CHUNK; tc++) {
        const int t = c * CHUNK + tc;
        const ushort_t* hb_in = (tc & 1) ? hb1 : hb0;
        ushort_t* hb_out      = (tc & 1) ? hb0 : hb1;

        // gate-precompute prefetch — issued FIRST (oldest outstanding VM op)
        u32x4 gpre;
        {
            int b = tid >> 2, g = tid & 3;
            const ushort_t* gp = Gc + ((size_t)(tc * 64 + b)) * 4096 + g * 1024 + u0;
            GLOAD16_CACHED(gpre, gp);
        }

        // issue ALL FOUR quarters' coherent loads up-front (32 x 16B per thread)
        u32x4 R0[8], R1[8], R2[8], R3[8];
        qload(hb_in, 0, tid, R0);
        qload(hb_in, 1, tid, R1);
        qload(hb_in, 2, tid, R2);
        qload(hb_in, 3, tid, R3);
        // outstanding: gpre(1) + 32 loads. vmcnt(24) -> gpre+R0 complete.
        asm volatile("s_waitcnt vmcnt(24)"
            : "+v"(R0[0]), "+v"(R0[1]), "+v"(R0[2]), "+v"(R0[3]),
              "+v"(R0[4]), "+v"(R0[5]), "+v"(R0[6]), "+v"(R0[7]), "+v"(gpre) :: "memory");
        qwrite(Hq0, tid, R0);
        WGBAR();

        f32x4 acc[2][2] = {};
        computeQ(Hq0, Ws, 0, mh, kg, lrow, quad, swz, acc);
        WAITVM8(16, R1);
        qwrite(Hq1, tid, R1);
        WGBAR();

        computeQ(Hq1, Ws, 1, mh, kg, lrow, quad, swz, acc);
        WAITVM8(8, R2);
        qwrite(Hq0, tid, R2);
        WGBAR();

        computeQ(Hq0, Ws, 2, mh, kg, lrow, quad, swz, acc);
        WAITVM8(0, R3);
        qwrite(Hq1, tid, R3);
        WGBAR();

        computeQ(Hq1, Ws, 3, mh, kg, lrow, quad, swz, acc);

        // write kg-partial S (C/D layout: col = lane&15, row = quad*4 + r)
#pragma unroll
        for (int m = 0; m < 2; m++)
#pragma unroll
            for (int n = 0; n < 2; n++)
#pragma unroll
                for (int r = 0; r < 4; r++)
                    S[kg * 64 * S_STRIDE + (mh + m * 16 + quad * 4 + r) * S_STRIDE
                      + n * 16 + lrow] = acc[m][n][r];
        // park gate-precompute in LDS
        {
            int b = tid >> 2, g = tid & 3;
            *(u32x4*)&Gg[b * 32 + g * 8] = gpre;
        }
        WGBAR();

        // ---- elementwise LSTM + retention blend (register state) ----
        float hn_s[2];
#pragma unroll
        for (int i = 0; i < 2; i++) {
            int lin = tid + i * 256;
            int b = lin >> 3, u = lin & 7;
            int brow = b * S_STRIDE;
            float si = S[brow + u]      + S[64 * S_STRIDE + brow + u]      + bf2f(Gg[b * 32 + u]);
            float sf = S[brow + 8 + u]  + S[64 * S_STRIDE + brow + 8 + u]  + bf2f(Gg[b * 32 + 8 + u]);
            float so = S[brow + 16 + u] + S[64 * S_STRIDE + brow + 16 + u] + bf2f(Gg[b * 32 + 16 + u]);
            float sc = S[brow + 24 + u] + S[64 * S_STRIDE + brow + 24 + u] + bf2f(Gg[b * 32 + 24 + u]);
            float it = 1.f / (1.f + __expf(-si));
            float ft = 1.f / (1.f + __expf(-sf));
            float ot = 1.f / (1.f + __expf(-so));
            float gt = 1.f - 2.f / (__expf(2.f * sc) + 1.f);   // NaN-safe tanh
            float cn = cf_r[i] * ft + it * gt;
            float tcn = 1.f - 2.f / (__expf(2.f * cn) + 1.f);  // NaN-safe tanh
            float hl = ot * tcn;
            float rr = ret_r[i];
            float hn = rr * hf_r[i] + (1.f - rr) * hl;
            cf_r[i] = cn;
            hf_r[i] = hn;
            hn_s[i] = hn;
            Hw[lin] = f2bf(hn);                                // gather for coherent store
        }
        WGBAR();   // Hw visible

        // gathered coherent h-out store: wave 0 only (64 x 16B).
        if (tid < 64) {
            u32x4 v = *(const u32x4*)&Hw[tid * 8];
            ushort_t* dst = hb_out + (size_t)tid * 1024 + u0;
            GSTORE16_COH(dst, v);
            asm volatile("s_waitcnt vmcnt(0)" ::: "memory");
        }
        // arrive: one atomic add per WG to its group counter (8 lines, 16-way each)
        if (tc < CHUNK - 1 && tid == 0)
            __hip_atomic_fetch_add(flags + (wg & 7) * 32, 1u,
                                   __ATOMIC_RELAXED, __HIP_MEMORY_SCOPE_AGENT);

        // out NT stores AFTER the release path (off the flag's critical path)
#pragma unroll
        for (int i = 0; i < 2; i++)
            __builtin_nontemporal_store(hn_s[i], &out[(size_t)t * 65536 + idx_r[i]]);

        // ---- grid barrier: wave0 polls the 8 counters (lane i -> i&7) ----
        if (tc < CHUNK - 1) {
            unsigned target = 16u * (kbase + (unsigned)tc + 1u);
            if (tid < 64) {
                const unsigned* cp = flags + (tid & 7) * 32;
                for (;;) {
                    unsigned v = __hip_atomic_load(cp, __ATOMIC_RELAXED,
                                                   __HIP_MEMORY_SCOPE_AGENT);
                    if (__all(v >= target)) break;
                }
            }
            WGBAR();
            asm volatile("s_waitcnt vmcnt(0)" ::: "memory");  // drain NT stores + poll
        }
    }

    // ---- write back chunk-boundary state ----
#pragma unroll
    for (int i = 0; i < 2; i++) {
        hf_g[idx_r[i]] = hf_r[i];
        cf_g[idx_r[i]] = cf_r[i];
    }
}

// ---------------------------------------------------------------------------
// Epilogue: append h_T and c_T (fp32) to d_out
// ---------------------------------------------------------------------------
__global__ __launch_bounds__(256) void epilogue_k(
    const float* __restrict__ hf_final, const float* __restrict__ cf,
    float* __restrict__ out)
{
    int i = blockIdx.x * 256 + threadIdx.x;  // 65536
    out[OUTS_ELEMS + i] = hf_final[i];
    out[OUTS_ELEMS + 65536 + i] = cf[i];
}

// ---------------------------------------------------------------------------
extern "C" void kernel_launch(void* const* d_in, const int* in_sizes, int n_in,
                              void* d_out, int out_size, void* d_ws, size_t ws_size,
                              hipStream_t stream)
{
    const float* input_ = (const float*)d_in[0];
    const float* h0   = (const float*)d_in[1];
    const float* c0   = (const float*)d_in[2];
    const float* w_xi = (const float*)d_in[3];
    const float* w_xf = (const float*)d_in[4];
    const float* w_xo = (const float*)d_in[5];
    const float* w_xc = (const float*)d_in[6];
    const float* w_hi = (const float*)d_in[7];
    const float* w_hf = (const float*)d_in[8];
    const float* w_ho = (const float*)d_in[9];
    const float* w_hc = (const float*)d_in[10];
    const float* b_i  = (const float*)d_in[11];
    const float* b_f  = (const float*)d_in[12];
    const float* b_o  = (const float*)d_in[13];
    const float* b_c  = (const float*)d_in[14];
    const float* ret  = (const float*)d_in[15];

    // workspace carve (~49 MiB): double-buffered gate chunks
    ushort_t* wt_x   = (ushort_t*)d_ws;            // 4*1M bf16  (8 MiB)
    ushort_t* wt_h   = wt_x + 4ULL * 1048576;      // 4*1M bf16  (8 MiB)
    ushort_t* g0     = wt_h + 4ULL * 1048576;      // 2048*4096 bf16 (16 MiB)
    ushort_t* g1     = g0 + (size_t)MCH * 4096;    // 2048*4096 bf16 (16 MiB)
    float*  cf  = (float*)(g1 + (size_t)MCH * 4096);
    float*  hf0 = cf + 65536;
    float*  hf1 = hf0 + 65536;                     // (unused; carve kept stable)
    ushort_t* hb0 = (ushort_t*)(hf1 + 65536);
    ushort_t* hb1 = hb0 + 65536;
    unsigned* flags = (unsigned*)(hb1 + 65536);    // 8 counters at [k*32] (1 KiB)
    float* out = (float*)d_out;

    static bool attr_set = false;
    if (!attr_set) {
        hipFuncSetAttribute(reinterpret_cast<const void*>(lstm_fused),
                            hipFuncAttributeMaxDynamicSharedMemorySize, SMEM_BYTES);
        attr_set = true;
    }

    Ptr8 p8; p8.p[0] = w_xi; p8.p[1] = w_xf; p8.p[2] = w_xo; p8.p[3] = w_xc;
             p8.p[4] = w_hi; p8.p[5] = w_hf; p8.p[6] = w_ho; p8.p[7] = w_hc;
    transpose8<<<dim3(16, 16, 8), 256, 0, stream>>>(p8, wt_x);

    init_state<<<256, 256, 0, stream>>>(h0, c0, hf0, cf, hb0, flags);

    Ptr4 b4; b4.p[0] = b_i; b4.p[1] = b_f; b4.p[2] = b_o; b4.p[3] = b_c;

    // chunk 0 gates up-front; chunks 1..15 computed inside lstm_fused c-1
    chunk_gemm<<<dim3(32, 16), 256, 0, stream>>>(input_, wt_x, b4, g0);

    for (int chunk = 0; chunk < NCHUNK; chunk++) {
        const ushort_t* gcur = (chunk & 1) ? g1 : g0;
        ushort_t* gnext      = (chunk & 1) ? g0 : g1;
        lstm_fused<<<2 * NWG, 256, SMEM_BYTES, stream>>>(
            wt_h, wt_x, gcur, gnext, input_, b4, ret, cf, hf0,
            hb0, hb1, out, flags, chunk);
    }

    epilogue_k<<<256, 256, 0, stream>>>(hf0, cf, out);
}